// Round 7
// baseline (810.885 us; speedup 1.0000x reference)
//
#include <hip/hip_runtime.h>

#define NND 8192
#define KNBR 8
#define DD 128
#define EPSF 1e-5f
#define BSTR 264    // LDS B-tile row stride in shorts
#define NBLK 512    // 2 blocks/CU -- half of guaranteed launch_bounds(256,4) capacity

typedef __attribute__((ext_vector_type(8))) short bf16x8;
typedef __attribute__((ext_vector_type(4))) float f32x4;

__device__ __forceinline__ unsigned short f2bf(float f) {
    unsigned u = __float_as_uint(f);
    u += 0x7FFF + ((u >> 16) & 1);   // round-to-nearest-even
    return (unsigned short)(u >> 16);
}

// ---------------------------------------------------------------------------
// Device-wide sense-reversal barrier (agent-scope atomics + threadfence).
// bar[0] = arrive counter, bar[32] = generation. Zeroed via hipMemsetAsync
// before launch. All NBLK blocks are co-resident (2/CU vs capacity 4/CU).
// ---------------------------------------------------------------------------
__device__ __forceinline__ void grid_barrier(unsigned* bar, unsigned nblk) {
    __syncthreads();
    if (threadIdx.x == 0) {
        unsigned* count = bar;
        unsigned* gen = bar + 32;
        __threadfence();   // flush this CU's writes to device-visible point
        unsigned g = __hip_atomic_load(gen, __ATOMIC_ACQUIRE, __HIP_MEMORY_SCOPE_AGENT);
        unsigned arrived = __hip_atomic_fetch_add(count, 1u, __ATOMIC_ACQ_REL,
                                                  __HIP_MEMORY_SCOPE_AGENT) + 1;
        if (arrived == nblk) {
            __hip_atomic_store(count, 0u, __ATOMIC_RELAXED, __HIP_MEMORY_SCOPE_AGENT);
            __hip_atomic_store(gen, g + 1u, __ATOMIC_RELEASE, __HIP_MEMORY_SCOPE_AGENT);
        } else {
            while (__hip_atomic_load(gen, __ATOMIC_ACQUIRE,
                                     __HIP_MEMORY_SCOPE_AGENT) == g) {
                __builtin_amdgcn_s_sleep(2);
            }
        }
        __threadfence();   // invalidate caches so we see others' writes
    }
    __syncthreads();
}

// Stage 16 x 128 fp32 W rows -> bf16 LDS tile (converts on the fly).
__device__ __forceinline__ void stage_b128f(unsigned short* sh,
        const float* __restrict__ W, int wstride, int tid) {
    int r = tid >> 4;
    int c = (tid & 15) * 8;
    const float* src = W + (size_t)r * wstride + c;
    float4 lo = *(const float4*)(src);
    float4 hi = *(const float4*)(src + 4);
    bf16x8 v;
    v[0] = f2bf(lo.x); v[1] = f2bf(lo.y); v[2] = f2bf(lo.z); v[3] = f2bf(lo.w);
    v[4] = f2bf(hi.x); v[5] = f2bf(hi.y); v[6] = f2bf(hi.z); v[7] = f2bf(hi.w);
    *(bf16x8*)(sh + r * BSTR + c) = v;
}

// Stage 16 x 256 fp32 W rows -> bf16 LDS tile.
__device__ __forceinline__ void stage_b256f(unsigned short* sh,
        const float* __restrict__ W, int wstride, int tid) {
    int r = tid >> 4;
    int c = (tid & 15) * 16;
    const float* src = W + (size_t)r * wstride + c;
#pragma unroll
    for (int h = 0; h < 2; ++h) {
        float4 lo = *(const float4*)(src + h * 8);
        float4 hi = *(const float4*)(src + h * 8 + 4);
        bf16x8 v;
        v[0] = f2bf(lo.x); v[1] = f2bf(lo.y); v[2] = f2bf(lo.z); v[3] = f2bf(lo.w);
        v[4] = f2bf(hi.x); v[5] = f2bf(hi.y); v[6] = f2bf(hi.z); v[7] = f2bf(hi.w);
        *(bf16x8*)(sh + r * BSTR + c + h * 8) = v;
    }
}

__device__ __forceinline__ bf16x8 afrag(const float* __restrict__ Arow, int k0) {
    float4 lo = *(const float4*)(Arow + k0);
    float4 hi = *(const float4*)(Arow + k0 + 4);
    bf16x8 r;
    r[0] = f2bf(lo.x); r[1] = f2bf(lo.y); r[2] = f2bf(lo.z); r[3] = f2bf(lo.w);
    r[4] = f2bf(hi.x); r[5] = f2bf(hi.y); r[6] = f2bf(hi.z); r[7] = f2bf(hi.w);
    return r;
}

// One 16x16 output tile, K=128 (4 mfma). Layouts per guide §3 (m89/m91):
// A[m=lane&15][k=quad*8+j], B[k][n] from W[n][k] 16B slices, C/D col=lane&15 row=quad*4+reg.
__device__ __forceinline__ f32x4 mma128(const float* __restrict__ A, int strideA,
                                        int rowBase, const unsigned short* shB,
                                        int lane, f32x4 acc) {
    int idx = lane & 15, q = lane >> 4;
    const float* Arow = A + (size_t)(rowBase + idx) * strideA;
#pragma unroll
    for (int s = 0; s < 4; ++s) {
        bf16x8 af = afrag(Arow, s * 32 + q * 8);
        bf16x8 bf = *(const bf16x8*)(shB + idx * BSTR + s * 32 + q * 8);
        acc = __builtin_amdgcn_mfma_f32_16x16x32_bf16(af, bf, acc, 0, 0, 0);
    }
    return acc;
}

__device__ __forceinline__ void store_tile(float* __restrict__ out, int ostride,
        int oOff, int rowBase, int colBase, int lane, f32x4 c,
        const float* __restrict__ bias, bool relu) {
    int idx = lane & 15, q = lane >> 4;
    float b = bias[colBase + idx];
#pragma unroll
    for (int r = 0; r < 4; ++r) {
        float v = c[r] + b;
        if (relu) v = fmaxf(v, 0.f);
        out[(size_t)(rowBase + q * 4 + r) * ostride + oOff + colBase + idx] = v;
    }
}

// ---------------------------------------------------------------------------
// Row-wise helpers (fp32, one wave per row, float2 per lane).
// ---------------------------------------------------------------------------
__device__ __forceinline__ float wave_sum(float s) {
#pragma unroll
    for (int m = 1; m < 64; m <<= 1) s += __shfl_xor(s, m, 64);
    return s;
}

__device__ __forceinline__ void prop_ln_row(int row, int lane,
        const float* __restrict__ nxt, const float* __restrict__ resid,
        const float* __restrict__ dinv, const int* __restrict__ kept,
        const int* __restrict__ neigh,
        const float* __restrict__ g, const float* __restrict__ b,
        float* __restrict__ out, int oStride, int oOff) {
    const float2* nxt2 = (const float2*)nxt;
    float di = dinv[row];
    int km = kept[row];
    float2 self = nxt2[row * 64 + lane];
    float ax = di * self.x, ay = di * self.y;
#pragma unroll
    for (int j = 0; j < KNBR; ++j) {
        if (km & (1 << j)) {
            int nb = neigh[row * KNBR + j];
            float dn = dinv[nb];
            float2 v = nxt2[nb * 64 + lane];
            ax = fmaf(dn, v.x, ax);
            ay = fmaf(dn, v.y, ay);
        }
    }
    float2 r = ((const float2*)resid)[row * 64 + lane];
    float vx = fmaxf(di * ax, 0.f) + r.x;
    float vy = fmaxf(di * ay, 0.f) + r.y;
    float mu = wave_sum(vx + vy) * (1.f / 128.f);
    float dx = vx - mu, dy = vy - mu;
    float var = wave_sum(dx * dx + dy * dy) * (1.f / 128.f);
    float rs = rsqrtf(var + EPSF);
    float2 gg = ((const float2*)g)[lane];
    float2 bb = ((const float2*)b)[lane];
    float2 o;
    o.x = dx * rs * gg.x + bb.x;
    o.y = dy * rs * gg.y + bb.y;
    *reinterpret_cast<float2*>(out + (size_t)row * oStride + oOff + lane * 2) = o;
}

__device__ __forceinline__ void pool_row(int row, int lane,
        const float* __restrict__ enc, const int* __restrict__ neigh,
        const int* __restrict__ cnt, float* __restrict__ P) {
    int c = cnt[row];
    float2 acc = make_float2(0.f, 0.f);
    if (c > 0) {
        acc = make_float2(-1e30f, -1e30f);
        for (int j = 0; j < c; ++j) {
            int nb = neigh[row * KNBR + j];
            float2 v = ((const float2*)enc)[nb * 64 + lane];
            acc.x = fmaxf(acc.x, v.x);
            acc.y = fmaxf(acc.y, v.y);
        }
    }
    ((float2*)P)[row * 64 + lane] = acc;
}

__device__ __forceinline__ void add_ln_row(int row, int lane,
        const float* __restrict__ nxt, const float* __restrict__ sprev,
        const float* __restrict__ g, const float* __restrict__ b,
        float* __restrict__ out, int oStride, int oOff) {
    float2 a = ((const float2*)nxt)[row * 64 + lane];
    float2 r = ((const float2*)sprev)[row * 64 + lane];
    float vx = a.x + r.x, vy = a.y + r.y;
    float mu = wave_sum(vx + vy) * (1.f / 128.f);
    float dx = vx - mu, dy = vy - mu;
    float var = wave_sum(dx * dx + dy * dy) * (1.f / 128.f);
    float rs = rsqrtf(var + EPSF);
    float2 gg = ((const float2*)g)[lane];
    float2 bb = ((const float2*)b)[lane];
    float2 o;
    o.x = dx * rs * gg.x + bb.x;
    o.y = dy * rs * gg.y + bb.y;
    *reinterpret_cast<float2*>(out + (size_t)row * oStride + oOff + lane * 2) = o;
}

// ---------------------------------------------------------------------------
// Single persistent kernel: 9 phases, 8 software grid barriers.
// ---------------------------------------------------------------------------
__global__ __launch_bounds__(256, 4)
void fused_all(const float* __restrict__ x, const int* __restrict__ neigh,
               const int* __restrict__ cnt,
               const float* __restrict__ gcnW, const float* __restrict__ gcnB,
               const float* __restrict__ gcnG, const float* __restrict__ gcnBb,
               const float* __restrict__ poolW, const float* __restrict__ poolB,
               const float* __restrict__ mW, const float* __restrict__ mB,
               const float* __restrict__ sg, const float* __restrict__ sb,
               float* __restrict__ out, unsigned* __restrict__ bar,
               float* __restrict__ dinv, int* __restrict__ kept,
               float* __restrict__ G, float* __restrict__ H1, float* __restrict__ H2,
               float* __restrict__ E, float* __restrict__ P,
               float* __restrict__ S1, float* __restrict__ S2, float* __restrict__ T) {
    __shared__ unsigned short shB[16 * BSTR];
    const int tid = threadIdx.x;
    const int lane = tid & 63;
    const int w = tid >> 6;
    const unsigned nb = gridDim.x;

    // ---- Phase 1: mega GEMM from x (3072 items) + deg/dedupe (32 items) ----
    for (int item = blockIdx.x; item < 3104; item += nb) {
        if (item < 3072) {
            int bx = item & 127;
            int by = item >> 7;
            int grp = by >> 3;
            int colBase = (by & 7) * 16;
            const float* W; const float* bias; float* dst; int wstr; bool relu = false;
            if (grp == 0)      { W = gcnW;  bias = gcnB;  dst = G;  wstr = 128; }
            else if (grp == 1) { W = poolW; bias = poolB; dst = E;  wstr = 128; relu = true; }
            else               { W = mW;    bias = mB;    dst = S1; wstr = 256; }
            stage_b128f(shB, W + (size_t)colBase * wstr, wstr, tid);
            __syncthreads();
            int rowBase = (bx * 4 + w) * 16;
            f32x4 acc = {0.f, 0.f, 0.f, 0.f};
            acc = mma128(x, DD, rowBase, shB, lane, acc);
            store_tile(dst, DD, 0, rowBase, colBase, lane, acc, bias, relu);
            __syncthreads();
        } else {
            int i = (item - 3072) * 256 + tid;
            int c = cnt[i];
            int nbv[KNBR];
#pragma unroll
            for (int j = 0; j < KNBR; ++j) nbv[j] = neigh[i * KNBR + j];
            int mask = 0, deg = 1;
#pragma unroll
            for (int j = 0; j < KNBR; ++j) {
                if (j < c) {
                    int v = nbv[j];
                    bool dup = (v == i);
                    for (int jj = 0; jj < j; ++jj)
                        if (nbv[jj] == v) { dup = true; }
                    if (!dup) { mask |= (1 << j); deg++; }
                }
            }
            dinv[i] = rsqrtf((float)deg);
            kept[i] = mask;
        }
    }
    grid_barrier(bar, nb);

    // ---- Phase 2: H1 = propLN(G0, resid=G0); P1 = pool(E1) ----
    for (int item = blockIdx.x; item < 2048; item += nb) {
        int row = item * 4 + w;
        prop_ln_row(row, lane, G, G, dinv, kept, neigh, gcnG, gcnBb, H1, DD, 0);
        pool_row(row, lane, E, neigh, cnt, P);
    }
    grid_barrier(bar, nb);

    // ---- Phase 3: z0: S1 = relu(S1p + P1@mW0R^T); z1: G1 = H1@gcnW1^T + b1 ----
    for (int item = blockIdx.x; item < 2048; item += nb) {
        int bx = item & 127, by = (item >> 7) & 7, bz = item >> 10;
        int colBase = by * 16;
        int rowBase = (bx * 4 + w) * 16;
        f32x4 acc = {0.f, 0.f, 0.f, 0.f};
        if (bz == 0) {
            stage_b128f(shB, mW + 128 + (size_t)colBase * 256, 256, tid);
            __syncthreads();
            acc = mma128(P, DD, rowBase, shB, lane, acc);
            int idx = lane & 15, q = lane >> 4;
#pragma unroll
            for (int r = 0; r < 4; ++r) {
                size_t o = (size_t)(rowBase + q * 4 + r) * DD + colBase + idx;
                S1[o] = fmaxf(S1[o] + acc[r], 0.f);
            }
            __syncthreads();
        } else {
            stage_b128f(shB, gcnW + DD * DD + (size_t)colBase * 128, 128, tid);
            __syncthreads();
            acc = mma128(H1, DD, rowBase, shB, lane, acc);
            store_tile(G, DD, 0, rowBase, colBase, lane, acc, gcnB + DD, false);
            __syncthreads();
        }
    }
    grid_barrier(bar, nb);

    // ---- Phase 4: H2 = propLN(G1, resid=H1); P2 = pool(S1) ----
    for (int item = blockIdx.x; item < 2048; item += nb) {
        int row = item * 4 + w;
        prop_ln_row(row, lane, G, H1, dinv, kept, neigh, gcnG + DD, gcnBb + DD, H2, DD, 0);
        pool_row(row, lane, S1, neigh, cnt, P);
    }
    grid_barrier(bar, nb);

    // ---- Phase 5: z0: T = relu([S1|P2]@mW1^T + mB1); z1: G2 = H2@gcnW2^T + b2 ----
    for (int item = blockIdx.x; item < 2048; item += nb) {
        int bx = item & 127, by = (item >> 7) & 7, bz = item >> 10;
        int colBase = by * 16;
        int rowBase = (bx * 4 + w) * 16;
        f32x4 acc = {0.f, 0.f, 0.f, 0.f};
        if (bz == 0) {
            stage_b256f(shB, mW + (size_t)DD * 2 * DD + (size_t)colBase * 256, 256, tid);
            __syncthreads();
            acc = mma128(S1, DD, rowBase, shB, lane, acc);
            acc = mma128(P, DD, rowBase, shB + 128, lane, acc);
            store_tile(T, DD, 0, rowBase, colBase, lane, acc, mB + DD, true);
            __syncthreads();
        } else {
            stage_b128f(shB, gcnW + 2 * DD * DD + (size_t)colBase * 128, 128, tid);
            __syncthreads();
            acc = mma128(H2, DD, rowBase, shB, lane, acc);
            store_tile(G, DD, 0, rowBase, colBase, lane, acc, gcnB + 2 * DD, false);
            __syncthreads();
        }
    }
    grid_barrier(bar, nb);

    // ---- Phase 6: outL = propLN(G2, resid=H2); S2 = LN(T + S1) ----
    for (int item = blockIdx.x; item < 2048; item += nb) {
        int row = item * 4 + w;
        prop_ln_row(row, lane, G, H2, dinv, kept, neigh, gcnG + 2 * DD, gcnBb + 2 * DD,
                    out, 2 * DD, 0);
        add_ln_row(row, lane, T, S1, sg, sb, S2, DD, 0);
    }
    grid_barrier(bar, nb);

    // ---- Phase 7: P3 = pool(S2) ----
    for (int item = blockIdx.x; item < 2048; item += nb) {
        int row = item * 4 + w;
        pool_row(row, lane, S2, neigh, cnt, P);
    }
    grid_barrier(bar, nb);

    // ---- Phase 8: T = relu([S2|P3]@mW2^T + mB2) ----
    for (int item = blockIdx.x; item < 1024; item += nb) {
        int bx = item & 127, by = item >> 7;
        int colBase = by * 16;
        int rowBase = (bx * 4 + w) * 16;
        stage_b256f(shB, mW + (size_t)2 * DD * 2 * DD + (size_t)colBase * 256, 256, tid);
        __syncthreads();
        f32x4 acc = {0.f, 0.f, 0.f, 0.f};
        acc = mma128(S2, DD, rowBase, shB, lane, acc);
        acc = mma128(P, DD, rowBase, shB + 128, lane, acc);
        store_tile(T, DD, 0, rowBase, colBase, lane, acc, mB + 2 * DD, true);
        __syncthreads();
    }
    grid_barrier(bar, nb);

    // ---- Phase 9: outR = LN(T + S2) ----
    for (int item = blockIdx.x; item < 2048; item += nb) {
        int row = item * 4 + w;
        add_ln_row(row, lane, T, S2, sg + DD, sb + DD, out, 2 * DD, DD);
    }
}

extern "C" void kernel_launch(void* const* d_in, const int* in_sizes, int n_in,
                              void* d_out, int out_size, void* d_ws, size_t ws_size,
                              hipStream_t stream) {
    (void)in_sizes; (void)n_in; (void)out_size; (void)ws_size;
    const float* x      = (const float*)d_in[0];
    const int*   neigh  = (const int*)d_in[1];
    const int*   cnt    = (const int*)d_in[2];
    const float* gcnW   = (const float*)d_in[3];
    const float* gcnB   = (const float*)d_in[4];
    const float* gcnG   = (const float*)d_in[5];
    const float* gcnBb  = (const float*)d_in[6];
    const float* poolW  = (const float*)d_in[7];
    const float* poolB  = (const float*)d_in[8];
    const float* mW     = (const float*)d_in[9];
    const float* mB     = (const float*)d_in[10];
    const float* sg     = (const float*)d_in[11];
    const float* sb     = (const float*)d_in[12];
    float* out = (float*)d_out;

    char* ws = (char*)d_ws;
    unsigned* bar = (unsigned*)ws;                    // 256 B barrier state
    float* dinv = (float*)(ws + 4 * 1024);            // 32 KB
    int*   kept = (int*)(ws + 36 * 1024);             // 32 KB
    float* G  = (float*)(ws + 68 * 1024);             // 4 MB each
    float* H1 = G  + NND * DD;
    float* H2 = H1 + NND * DD;
    float* E  = H2 + NND * DD;
    float* P  = E  + NND * DD;
    float* S1 = P  + NND * DD;
    float* S2 = S1 + NND * DD;
    float* T  = S2 + NND * DD;

    // zero barrier state (capture-safe stream op; harness uses the same API)
    hipMemsetAsync(bar, 0, 256, stream);

    fused_all<<<dim3(NBLK), dim3(256), 0, stream>>>(
        x, neigh, cnt, gcnW, gcnB, gcnG, gcnBb, poolW, poolB, mW, mB,
        sg, sb, out, bar, dinv, kept, G, H1, H2, E, P, S1, S2, T);
}

// Round 8
// 651.448 us; speedup vs baseline: 1.2447x; 1.2447x over previous
//
#include <hip/hip_runtime.h>

#define NND 8192
#define KNBR 8
#define DD 128
#define EPSF 1e-5f
#define BSTR 264    // LDS B-tile row stride in shorts
#define NBLK 512    // 2 blocks/CU -- half of guaranteed launch_bounds(256,4) capacity

typedef __attribute__((ext_vector_type(8))) short bf16x8;
typedef __attribute__((ext_vector_type(4))) float f32x4;

__device__ __forceinline__ unsigned short f2bf(float f) {
    unsigned u = __float_as_uint(f);
    u += 0x7FFF + ((u >> 16) & 1);   // round-to-nearest-even
    return (unsigned short)(u >> 16);
}

// ---------------------------------------------------------------------------
// Device-wide barrier, monotonic-counter flavor. bar[0] only; zeroed by
// hipMemsetAsync before launch. Phase p waits for count >= NBLK*p.
// RELAXED spin => no per-iteration cache maintenance (the R7 killer was an
// ACQUIRE spin emitting L2-invalidates per iteration: 750us, FETCH 73MB).
// Exactly two __threadfence() per block per barrier give cross-XCD ordering.
// ---------------------------------------------------------------------------
__device__ __forceinline__ void grid_barrier(unsigned* bar, unsigned nblk,
                                             unsigned phase) {
    __syncthreads();
    if (threadIdx.x == 0) {
        __threadfence();   // release: push this XCD's dirty lines device-visible
        __hip_atomic_fetch_add(bar, 1u, __ATOMIC_RELAXED, __HIP_MEMORY_SCOPE_AGENT);
        const unsigned target = nblk * phase;
        while (__hip_atomic_load(bar, __ATOMIC_RELAXED,
                                 __HIP_MEMORY_SCOPE_AGENT) < target) {
            __builtin_amdgcn_s_sleep(4);
        }
        __threadfence();   // acquire: drop stale lines before reading others' data
    }
    __syncthreads();
}

// Stage 16 x 128 fp32 W rows -> bf16 LDS tile (converts on the fly).
__device__ __forceinline__ void stage_b128f(unsigned short* sh,
        const float* __restrict__ W, int wstride, int tid) {
    int r = tid >> 4;
    int c = (tid & 15) * 8;
    const float* src = W + (size_t)r * wstride + c;
    float4 lo = *(const float4*)(src);
    float4 hi = *(const float4*)(src + 4);
    bf16x8 v;
    v[0] = f2bf(lo.x); v[1] = f2bf(lo.y); v[2] = f2bf(lo.z); v[3] = f2bf(lo.w);
    v[4] = f2bf(hi.x); v[5] = f2bf(hi.y); v[6] = f2bf(hi.z); v[7] = f2bf(hi.w);
    *(bf16x8*)(sh + r * BSTR + c) = v;
}

// Stage 16 x 256 fp32 W rows -> bf16 LDS tile.
__device__ __forceinline__ void stage_b256f(unsigned short* sh,
        const float* __restrict__ W, int wstride, int tid) {
    int r = tid >> 4;
    int c = (tid & 15) * 16;
    const float* src = W + (size_t)r * wstride + c;
#pragma unroll
    for (int h = 0; h < 2; ++h) {
        float4 lo = *(const float4*)(src + h * 8);
        float4 hi = *(const float4*)(src + h * 8 + 4);
        bf16x8 v;
        v[0] = f2bf(lo.x); v[1] = f2bf(lo.y); v[2] = f2bf(lo.z); v[3] = f2bf(lo.w);
        v[4] = f2bf(hi.x); v[5] = f2bf(hi.y); v[6] = f2bf(hi.z); v[7] = f2bf(hi.w);
        *(bf16x8*)(sh + r * BSTR + c + h * 8) = v;
    }
}

__device__ __forceinline__ bf16x8 afrag(const float* __restrict__ Arow, int k0) {
    float4 lo = *(const float4*)(Arow + k0);
    float4 hi = *(const float4*)(Arow + k0 + 4);
    bf16x8 r;
    r[0] = f2bf(lo.x); r[1] = f2bf(lo.y); r[2] = f2bf(lo.z); r[3] = f2bf(lo.w);
    r[4] = f2bf(hi.x); r[5] = f2bf(hi.y); r[6] = f2bf(hi.z); r[7] = f2bf(hi.w);
    return r;
}

// One 16x16 output tile, K=128 (4 mfma). Layouts per guide §3 (m89/m91):
// A[m=lane&15][k=quad*8+j], B[k][n] from W[n][k] 16B slices, C/D col=lane&15 row=quad*4+reg.
__device__ __forceinline__ f32x4 mma128(const float* __restrict__ A, int strideA,
                                        int rowBase, const unsigned short* shB,
                                        int lane, f32x4 acc) {
    int idx = lane & 15, q = lane >> 4;
    const float* Arow = A + (size_t)(rowBase + idx) * strideA;
#pragma unroll
    for (int s = 0; s < 4; ++s) {
        bf16x8 af = afrag(Arow, s * 32 + q * 8);
        bf16x8 bf = *(const bf16x8*)(shB + idx * BSTR + s * 32 + q * 8);
        acc = __builtin_amdgcn_mfma_f32_16x16x32_bf16(af, bf, acc, 0, 0, 0);
    }
    return acc;
}

__device__ __forceinline__ void store_tile(float* __restrict__ out, int ostride,
        int oOff, int rowBase, int colBase, int lane, f32x4 c,
        const float* __restrict__ bias, bool relu) {
    int idx = lane & 15, q = lane >> 4;
    float b = bias[colBase + idx];
#pragma unroll
    for (int r = 0; r < 4; ++r) {
        float v = c[r] + b;
        if (relu) v = fmaxf(v, 0.f);
        out[(size_t)(rowBase + q * 4 + r) * ostride + oOff + colBase + idx] = v;
    }
}

// ---------------------------------------------------------------------------
// Row-wise helpers (fp32, one wave per row, float2 per lane).
// ---------------------------------------------------------------------------
__device__ __forceinline__ float wave_sum(float s) {
#pragma unroll
    for (int m = 1; m < 64; m <<= 1) s += __shfl_xor(s, m, 64);
    return s;
}

__device__ __forceinline__ void prop_ln_row(int row, int lane,
        const float* __restrict__ nxt, const float* __restrict__ resid,
        const float* __restrict__ dinv, const int* __restrict__ kept,
        const int* __restrict__ neigh,
        const float* __restrict__ g, const float* __restrict__ b,
        float* __restrict__ out, int oStride, int oOff) {
    const float2* nxt2 = (const float2*)nxt;
    float di = dinv[row];
    int km = kept[row];
    float2 self = nxt2[row * 64 + lane];
    float ax = di * self.x, ay = di * self.y;
#pragma unroll
    for (int j = 0; j < KNBR; ++j) {
        if (km & (1 << j)) {
            int nb = neigh[row * KNBR + j];
            float dn = dinv[nb];
            float2 v = nxt2[nb * 64 + lane];
            ax = fmaf(dn, v.x, ax);
            ay = fmaf(dn, v.y, ay);
        }
    }
    float2 r = ((const float2*)resid)[row * 64 + lane];
    float vx = fmaxf(di * ax, 0.f) + r.x;
    float vy = fmaxf(di * ay, 0.f) + r.y;
    float mu = wave_sum(vx + vy) * (1.f / 128.f);
    float dx = vx - mu, dy = vy - mu;
    float var = wave_sum(dx * dx + dy * dy) * (1.f / 128.f);
    float rs = rsqrtf(var + EPSF);
    float2 gg = ((const float2*)g)[lane];
    float2 bb = ((const float2*)b)[lane];
    float2 o;
    o.x = dx * rs * gg.x + bb.x;
    o.y = dy * rs * gg.y + bb.y;
    *reinterpret_cast<float2*>(out + (size_t)row * oStride + oOff + lane * 2) = o;
}

__device__ __forceinline__ void pool_row(int row, int lane,
        const float* __restrict__ enc, const int* __restrict__ neigh,
        const int* __restrict__ cnt, float* __restrict__ P) {
    int c = cnt[row];
    float2 acc = make_float2(0.f, 0.f);
    if (c > 0) {
        acc = make_float2(-1e30f, -1e30f);
        for (int j = 0; j < c; ++j) {
            int nb = neigh[row * KNBR + j];
            float2 v = ((const float2*)enc)[nb * 64 + lane];
            acc.x = fmaxf(acc.x, v.x);
            acc.y = fmaxf(acc.y, v.y);
        }
    }
    ((float2*)P)[row * 64 + lane] = acc;
}

__device__ __forceinline__ void add_ln_row(int row, int lane,
        const float* __restrict__ nxt, const float* __restrict__ sprev,
        const float* __restrict__ g, const float* __restrict__ b,
        float* __restrict__ out, int oStride, int oOff) {
    float2 a = ((const float2*)nxt)[row * 64 + lane];
    float2 r = ((const float2*)sprev)[row * 64 + lane];
    float vx = a.x + r.x, vy = a.y + r.y;
    float mu = wave_sum(vx + vy) * (1.f / 128.f);
    float dx = vx - mu, dy = vy - mu;
    float var = wave_sum(dx * dx + dy * dy) * (1.f / 128.f);
    float rs = rsqrtf(var + EPSF);
    float2 gg = ((const float2*)g)[lane];
    float2 bb = ((const float2*)b)[lane];
    float2 o;
    o.x = dx * rs * gg.x + bb.x;
    o.y = dy * rs * gg.y + bb.y;
    *reinterpret_cast<float2*>(out + (size_t)row * oStride + oOff + lane * 2) = o;
}

// ---------------------------------------------------------------------------
// Single persistent kernel: 9 phases, 8 software grid barriers.
// ---------------------------------------------------------------------------
__global__ __launch_bounds__(256, 4)
void fused_all(const float* __restrict__ x, const int* __restrict__ neigh,
               const int* __restrict__ cnt,
               const float* __restrict__ gcnW, const float* __restrict__ gcnB,
               const float* __restrict__ gcnG, const float* __restrict__ gcnBb,
               const float* __restrict__ poolW, const float* __restrict__ poolB,
               const float* __restrict__ mW, const float* __restrict__ mB,
               const float* __restrict__ sg, const float* __restrict__ sb,
               float* __restrict__ out, unsigned* __restrict__ bar,
               float* __restrict__ dinv, int* __restrict__ kept,
               float* __restrict__ G, float* __restrict__ H1, float* __restrict__ H2,
               float* __restrict__ E, float* __restrict__ P,
               float* __restrict__ S1, float* __restrict__ S2, float* __restrict__ T) {
    __shared__ unsigned short shB[16 * BSTR];
    const int tid = threadIdx.x;
    const int lane = tid & 63;
    const int w = tid >> 6;
    const unsigned nb = gridDim.x;

    // ---- Phase 1: mega GEMM from x (3072 items) + deg/dedupe (32 items) ----
    for (int item = blockIdx.x; item < 3104; item += nb) {
        if (item < 3072) {
            int bx = item & 127;
            int by = item >> 7;
            int grp = by >> 3;
            int colBase = (by & 7) * 16;
            const float* W; const float* bias; float* dst; int wstr; bool relu = false;
            if (grp == 0)      { W = gcnW;  bias = gcnB;  dst = G;  wstr = 128; }
            else if (grp == 1) { W = poolW; bias = poolB; dst = E;  wstr = 128; relu = true; }
            else               { W = mW;    bias = mB;    dst = S1; wstr = 256; }
            stage_b128f(shB, W + (size_t)colBase * wstr, wstr, tid);
            __syncthreads();
            int rowBase = (bx * 4 + w) * 16;
            f32x4 acc = {0.f, 0.f, 0.f, 0.f};
            acc = mma128(x, DD, rowBase, shB, lane, acc);
            store_tile(dst, DD, 0, rowBase, colBase, lane, acc, bias, relu);
            __syncthreads();
        } else {
            int i = (item - 3072) * 256 + tid;
            int c = cnt[i];
            int nbv[KNBR];
#pragma unroll
            for (int j = 0; j < KNBR; ++j) nbv[j] = neigh[i * KNBR + j];
            int mask = 0, deg = 1;
#pragma unroll
            for (int j = 0; j < KNBR; ++j) {
                if (j < c) {
                    int v = nbv[j];
                    bool dup = (v == i);
                    for (int jj = 0; jj < j; ++jj)
                        if (nbv[jj] == v) { dup = true; }
                    if (!dup) { mask |= (1 << j); deg++; }
                }
            }
            dinv[i] = rsqrtf((float)deg);
            kept[i] = mask;
        }
    }
    grid_barrier(bar, nb, 1);

    // ---- Phase 2: H1 = propLN(G0, resid=G0); P1 = pool(E1) ----
    for (int item = blockIdx.x; item < 2048; item += nb) {
        int row = item * 4 + w;
        prop_ln_row(row, lane, G, G, dinv, kept, neigh, gcnG, gcnBb, H1, DD, 0);
        pool_row(row, lane, E, neigh, cnt, P);
    }
    grid_barrier(bar, nb, 2);

    // ---- Phase 3: z0: S1 = relu(S1p + P1@mW0R^T); z1: G1 = H1@gcnW1^T + b1 ----
    for (int item = blockIdx.x; item < 2048; item += nb) {
        int bx = item & 127, by = (item >> 7) & 7, bz = item >> 10;
        int colBase = by * 16;
        int rowBase = (bx * 4 + w) * 16;
        f32x4 acc = {0.f, 0.f, 0.f, 0.f};
        if (bz == 0) {
            stage_b128f(shB, mW + 128 + (size_t)colBase * 256, 256, tid);
            __syncthreads();
            acc = mma128(P, DD, rowBase, shB, lane, acc);
            int idx = lane & 15, q = lane >> 4;
#pragma unroll
            for (int r = 0; r < 4; ++r) {
                size_t o = (size_t)(rowBase + q * 4 + r) * DD + colBase + idx;
                S1[o] = fmaxf(S1[o] + acc[r], 0.f);
            }
            __syncthreads();
        } else {
            stage_b128f(shB, gcnW + DD * DD + (size_t)colBase * 128, 128, tid);
            __syncthreads();
            acc = mma128(H1, DD, rowBase, shB, lane, acc);
            store_tile(G, DD, 0, rowBase, colBase, lane, acc, gcnB + DD, false);
            __syncthreads();
        }
    }
    grid_barrier(bar, nb, 3);

    // ---- Phase 4: H2 = propLN(G1, resid=H1); P2 = pool(S1) ----
    for (int item = blockIdx.x; item < 2048; item += nb) {
        int row = item * 4 + w;
        prop_ln_row(row, lane, G, H1, dinv, kept, neigh, gcnG + DD, gcnBb + DD, H2, DD, 0);
        pool_row(row, lane, S1, neigh, cnt, P);
    }
    grid_barrier(bar, nb, 4);

    // ---- Phase 5: z0: T = relu([S1|P2]@mW1^T + mB1); z1: G2 = H2@gcnW2^T + b2 ----
    for (int item = blockIdx.x; item < 2048; item += nb) {
        int bx = item & 127, by = (item >> 7) & 7, bz = item >> 10;
        int colBase = by * 16;
        int rowBase = (bx * 4 + w) * 16;
        f32x4 acc = {0.f, 0.f, 0.f, 0.f};
        if (bz == 0) {
            stage_b256f(shB, mW + (size_t)DD * 2 * DD + (size_t)colBase * 256, 256, tid);
            __syncthreads();
            acc = mma128(S1, DD, rowBase, shB, lane, acc);
            acc = mma128(P, DD, rowBase, shB + 128, lane, acc);
            store_tile(T, DD, 0, rowBase, colBase, lane, acc, mB + DD, true);
            __syncthreads();
        } else {
            stage_b128f(shB, gcnW + 2 * DD * DD + (size_t)colBase * 128, 128, tid);
            __syncthreads();
            acc = mma128(H2, DD, rowBase, shB, lane, acc);
            store_tile(G, DD, 0, rowBase, colBase, lane, acc, gcnB + 2 * DD, false);
            __syncthreads();
        }
    }
    grid_barrier(bar, nb, 5);

    // ---- Phase 6: outL = propLN(G2, resid=H2); S2 = LN(T + S1) ----
    for (int item = blockIdx.x; item < 2048; item += nb) {
        int row = item * 4 + w;
        prop_ln_row(row, lane, G, H2, dinv, kept, neigh, gcnG + 2 * DD, gcnBb + 2 * DD,
                    out, 2 * DD, 0);
        add_ln_row(row, lane, T, S1, sg, sb, S2, DD, 0);
    }
    grid_barrier(bar, nb, 6);

    // ---- Phase 7: P3 = pool(S2) ----
    for (int item = blockIdx.x; item < 2048; item += nb) {
        int row = item * 4 + w;
        pool_row(row, lane, S2, neigh, cnt, P);
    }
    grid_barrier(bar, nb, 7);

    // ---- Phase 8: T = relu([S2|P3]@mW2^T + mB2) ----
    for (int item = blockIdx.x; item < 1024; item += nb) {
        int bx = item & 127, by = item >> 7;
        int colBase = by * 16;
        int rowBase = (bx * 4 + w) * 16;
        stage_b256f(shB, mW + (size_t)2 * DD * 2 * DD + (size_t)colBase * 256, 256, tid);
        __syncthreads();
        f32x4 acc = {0.f, 0.f, 0.f, 0.f};
        acc = mma128(S2, DD, rowBase, shB, lane, acc);
        acc = mma128(P, DD, rowBase, shB + 128, lane, acc);
        store_tile(T, DD, 0, rowBase, colBase, lane, acc, mB + 2 * DD, true);
        __syncthreads();
    }
    grid_barrier(bar, nb, 8);

    // ---- Phase 9: outR = LN(T + S2) ----
    for (int item = blockIdx.x; item < 2048; item += nb) {
        int row = item * 4 + w;
        add_ln_row(row, lane, T, S2, sg + DD, sb + DD, out, 2 * DD, DD);
    }
}

extern "C" void kernel_launch(void* const* d_in, const int* in_sizes, int n_in,
                              void* d_out, int out_size, void* d_ws, size_t ws_size,
                              hipStream_t stream) {
    (void)in_sizes; (void)n_in; (void)out_size; (void)ws_size;
    const float* x      = (const float*)d_in[0];
    const int*   neigh  = (const int*)d_in[1];
    const int*   cnt    = (const int*)d_in[2];
    const float* gcnW   = (const float*)d_in[3];
    const float* gcnB   = (const float*)d_in[4];
    const float* gcnG   = (const float*)d_in[5];
    const float* gcnBb  = (const float*)d_in[6];
    const float* poolW  = (const float*)d_in[7];
    const float* poolB  = (const float*)d_in[8];
    const float* mW     = (const float*)d_in[9];
    const float* mB     = (const float*)d_in[10];
    const float* sg     = (const float*)d_in[11];
    const float* sb     = (const float*)d_in[12];
    float* out = (float*)d_out;

    char* ws = (char*)d_ws;
    unsigned* bar = (unsigned*)ws;                    // barrier counter (zeroed below)
    float* dinv = (float*)(ws + 4 * 1024);            // 32 KB
    int*   kept = (int*)(ws + 36 * 1024);             // 32 KB
    float* G  = (float*)(ws + 68 * 1024);             // 4 MB each
    float* H1 = G  + NND * DD;
    float* H2 = H1 + NND * DD;
    float* E  = H2 + NND * DD;
    float* P  = E  + NND * DD;
    float* S1 = P  + NND * DD;
    float* S2 = S1 + NND * DD;
    float* T  = S2 + NND * DD;

    // zero barrier state (capture-safe stream op)
    hipMemsetAsync(bar, 0, 256, stream);

    fused_all<<<dim3(NBLK), dim3(256), 0, stream>>>(
        x, neigh, cnt, gcnW, gcnB, gcnG, gcnBb, poolW, poolB, mW, mB,
        sg, sb, out, bar, dinv, kept, G, H1, H2, E, P, S1, S2, T);
}

// Round 9
// 443.925 us; speedup vs baseline: 1.8266x; 1.4675x over previous
//
#include <hip/hip_runtime.h>

#define NND 8192
#define KNBR 8
#define DD 128
#define EPSF 1e-5f
#define BSTR 264    // LDS B-tile row stride in shorts
#define NBLK 512    // 2 blocks/CU -- proven co-resident

typedef __attribute__((ext_vector_type(8))) short bf16x8;
typedef __attribute__((ext_vector_type(4))) float f32x4;

// ---------------------------------------------------------------------------
// Coherent (cross-XCD) loads/stores: relaxed agent-scope atomics compile to
// sc1-flagged global ops that bypass the per-XCD L2 and hit the device
// coherence point (Infinity Cache). No fences, no L2 writeback/invalidate.
// (R8 post-mortem: __threadfence = full-L2 wbl2/inv per block per barrier
//  => 8192 L2 flushes, 73MB refetch, 577us. This kills that.)
// ---------------------------------------------------------------------------
__device__ __forceinline__ float2 ldc8(const float* p) {
    unsigned long long v = __hip_atomic_load((const unsigned long long*)p,
                                             __ATOMIC_RELAXED, __HIP_MEMORY_SCOPE_AGENT);
    union { unsigned long long u; float2 f; } c; c.u = v; return c.f;
}
__device__ __forceinline__ void stc8(float* p, float2 f) {
    union { unsigned long long u; float2 f; } c; c.f = f;
    __hip_atomic_store((unsigned long long*)p, c.u,
                       __ATOMIC_RELAXED, __HIP_MEMORY_SCOPE_AGENT);
}
__device__ __forceinline__ float ldc4(const float* p) {
    unsigned v = __hip_atomic_load((const unsigned*)p,
                                   __ATOMIC_RELAXED, __HIP_MEMORY_SCOPE_AGENT);
    return __uint_as_float(v);
}
__device__ __forceinline__ void stc4(float* p, float v) {
    __hip_atomic_store((unsigned*)p, __float_as_uint(v),
                       __ATOMIC_RELAXED, __HIP_MEMORY_SCOPE_AGENT);
}
__device__ __forceinline__ int ldci(const int* p) {
    return (int)__hip_atomic_load((const unsigned*)p,
                                  __ATOMIC_RELAXED, __HIP_MEMORY_SCOPE_AGENT);
}
__device__ __forceinline__ void stci(int* p, int v) {
    __hip_atomic_store((unsigned*)p, (unsigned)v,
                       __ATOMIC_RELAXED, __HIP_MEMORY_SCOPE_AGENT);
}

__device__ __forceinline__ unsigned short f2bf(float f) {
    unsigned u = __float_as_uint(f);
    u += 0x7FFF + ((u >> 16) & 1);   // round-to-nearest-even
    return (unsigned short)(u >> 16);
}

// ---------------------------------------------------------------------------
// Fence-free device barrier. All data traffic is sc1-coherent, so ordering
// needs only: drain my outstanding stores (vmcnt 0), bump counter, spin.
// Monotonic target per phase; bar zeroed by hipMemsetAsync pre-launch.
// ---------------------------------------------------------------------------
__device__ __forceinline__ void grid_barrier(unsigned* bar, unsigned nblk,
                                             unsigned phase) {
    __syncthreads();
    if (threadIdx.x == 0) {
        __asm__ __volatile__("s_waitcnt vmcnt(0)" ::: "memory");
        __hip_atomic_fetch_add(bar, 1u, __ATOMIC_RELAXED, __HIP_MEMORY_SCOPE_AGENT);
        const unsigned target = nblk * phase;
        while (__hip_atomic_load(bar, __ATOMIC_RELAXED,
                                 __HIP_MEMORY_SCOPE_AGENT) < target) {
            __builtin_amdgcn_s_sleep(8);
        }
    }
    __syncthreads();
}

// Stage 16 x 128 fp32 W rows (read-only input -> cached loads) -> bf16 LDS.
__device__ __forceinline__ void stage_b128f(unsigned short* sh,
        const float* __restrict__ W, int wstride, int tid) {
    int r = tid >> 4;
    int c = (tid & 15) * 8;
    const float* src = W + (size_t)r * wstride + c;
    float4 lo = *(const float4*)(src);
    float4 hi = *(const float4*)(src + 4);
    bf16x8 v;
    v[0] = f2bf(lo.x); v[1] = f2bf(lo.y); v[2] = f2bf(lo.z); v[3] = f2bf(lo.w);
    v[4] = f2bf(hi.x); v[5] = f2bf(hi.y); v[6] = f2bf(hi.z); v[7] = f2bf(hi.w);
    *(bf16x8*)(sh + r * BSTR + c) = v;
}

__device__ __forceinline__ void stage_b256f(unsigned short* sh,
        const float* __restrict__ W, int wstride, int tid) {
    int r = tid >> 4;
    int c = (tid & 15) * 16;
    const float* src = W + (size_t)r * wstride + c;
#pragma unroll
    for (int h = 0; h < 2; ++h) {
        float4 lo = *(const float4*)(src + h * 8);
        float4 hi = *(const float4*)(src + h * 8 + 4);
        bf16x8 v;
        v[0] = f2bf(lo.x); v[1] = f2bf(lo.y); v[2] = f2bf(lo.z); v[3] = f2bf(lo.w);
        v[4] = f2bf(hi.x); v[5] = f2bf(hi.y); v[6] = f2bf(hi.z); v[7] = f2bf(hi.w);
        *(bf16x8*)(sh + r * BSTR + c + h * 8) = v;
    }
}

// A fragment: COH=true reads via coherent 8B loads (cross-phase buffers),
// COH=false reads via cached float4 (kernel inputs like x).
template <bool COH>
__device__ __forceinline__ bf16x8 afrag(const float* __restrict__ Arow, int k0) {
    bf16x8 r;
    if (COH) {
        float2 a = ldc8(Arow + k0),     b = ldc8(Arow + k0 + 2);
        float2 c = ldc8(Arow + k0 + 4), d = ldc8(Arow + k0 + 6);
        r[0] = f2bf(a.x); r[1] = f2bf(a.y); r[2] = f2bf(b.x); r[3] = f2bf(b.y);
        r[4] = f2bf(c.x); r[5] = f2bf(c.y); r[6] = f2bf(d.x); r[7] = f2bf(d.y);
    } else {
        float4 lo = *(const float4*)(Arow + k0);
        float4 hi = *(const float4*)(Arow + k0 + 4);
        r[0] = f2bf(lo.x); r[1] = f2bf(lo.y); r[2] = f2bf(lo.z); r[3] = f2bf(lo.w);
        r[4] = f2bf(hi.x); r[5] = f2bf(hi.y); r[6] = f2bf(hi.z); r[7] = f2bf(hi.w);
    }
    return r;
}

// One 16x16 output tile, K=128 (4 mfma). Layouts per guide §3 (m89/m91).
template <bool COH>
__device__ __forceinline__ f32x4 mma128(const float* __restrict__ A, int strideA,
                                        int rowBase, const unsigned short* shB,
                                        int lane, f32x4 acc) {
    int idx = lane & 15, q = lane >> 4;
    const float* Arow = A + (size_t)(rowBase + idx) * strideA;
#pragma unroll
    for (int s = 0; s < 4; ++s) {
        bf16x8 af = afrag<COH>(Arow, s * 32 + q * 8);
        bf16x8 bf = *(const bf16x8*)(shB + idx * BSTR + s * 32 + q * 8);
        acc = __builtin_amdgcn_mfma_f32_16x16x32_bf16(af, bf, acc, 0, 0, 0);
    }
    return acc;
}

// COH=true: coherent 4B stores (tile read by later phase). bias: cached.
template <bool COH>
__device__ __forceinline__ void store_tile(float* __restrict__ out, int ostride,
        int oOff, int rowBase, int colBase, int lane, f32x4 c,
        const float* __restrict__ bias, bool relu) {
    int idx = lane & 15, q = lane >> 4;
    float b = bias[colBase + idx];
#pragma unroll
    for (int r = 0; r < 4; ++r) {
        float v = c[r] + b;
        if (relu) v = fmaxf(v, 0.f);
        float* p = out + (size_t)(rowBase + q * 4 + r) * ostride + oOff + colBase + idx;
        if (COH) stc4(p, v); else *p = v;
    }
}

// ---------------------------------------------------------------------------
// Row-wise helpers. All cross-phase inputs via coherent loads.
// ---------------------------------------------------------------------------
__device__ __forceinline__ float wave_sum(float s) {
#pragma unroll
    for (int m = 1; m < 64; m <<= 1) s += __shfl_xor(s, m, 64);
    return s;
}

template <bool OUTC>
__device__ __forceinline__ void prop_ln_row(int row, int lane,
        const float* __restrict__ nxt, const float* __restrict__ resid,
        const float* __restrict__ dinv, const int* __restrict__ kept,
        const int* __restrict__ neigh,
        const float* __restrict__ g, const float* __restrict__ b,
        float* __restrict__ out, int oStride, int oOff) {
    float di = ldc4(dinv + row);
    int km = ldci(kept + row);
    float2 self = ldc8(nxt + row * DD + lane * 2);
    float ax = di * self.x, ay = di * self.y;
#pragma unroll
    for (int j = 0; j < KNBR; ++j) {
        if (km & (1 << j)) {
            int nb = neigh[row * KNBR + j];
            float dn = ldc4(dinv + nb);
            float2 v = ldc8(nxt + nb * DD + lane * 2);
            ax = fmaf(dn, v.x, ax);
            ay = fmaf(dn, v.y, ay);
        }
    }
    float2 r = ldc8(resid + row * DD + lane * 2);
    float vx = fmaxf(di * ax, 0.f) + r.x;
    float vy = fmaxf(di * ay, 0.f) + r.y;
    float mu = wave_sum(vx + vy) * (1.f / 128.f);
    float dx = vx - mu, dy = vy - mu;
    float var = wave_sum(dx * dx + dy * dy) * (1.f / 128.f);
    float rs = rsqrtf(var + EPSF);
    float2 gg = ((const float2*)g)[lane];
    float2 bb = ((const float2*)b)[lane];
    float2 o;
    o.x = dx * rs * gg.x + bb.x;
    o.y = dy * rs * gg.y + bb.y;
    float* p = out + (size_t)row * oStride + oOff + lane * 2;
    if (OUTC) stc8(p, o); else *reinterpret_cast<float2*>(p) = o;
}

__device__ __forceinline__ void pool_row(int row, int lane,
        const float* __restrict__ enc, const int* __restrict__ neigh,
        const int* __restrict__ cnt, float* __restrict__ P) {
    int c = cnt[row];
    float2 acc = make_float2(0.f, 0.f);
    if (c > 0) {
        acc = make_float2(-1e30f, -1e30f);
        for (int j = 0; j < c; ++j) {
            int nb = neigh[row * KNBR + j];
            float2 v = ldc8(enc + nb * DD + lane * 2);
            acc.x = fmaxf(acc.x, v.x);
            acc.y = fmaxf(acc.y, v.y);
        }
    }
    stc8(P + row * DD + lane * 2, acc);
}

template <bool OUTC>
__device__ __forceinline__ void add_ln_row(int row, int lane,
        const float* __restrict__ nxt, const float* __restrict__ sprev,
        const float* __restrict__ g, const float* __restrict__ b,
        float* __restrict__ out, int oStride, int oOff) {
    float2 a = ldc8(nxt + row * DD + lane * 2);
    float2 r = ldc8(sprev + row * DD + lane * 2);
    float vx = a.x + r.x, vy = a.y + r.y;
    float mu = wave_sum(vx + vy) * (1.f / 128.f);
    float dx = vx - mu, dy = vy - mu;
    float var = wave_sum(dx * dx + dy * dy) * (1.f / 128.f);
    float rs = rsqrtf(var + EPSF);
    float2 gg = ((const float2*)g)[lane];
    float2 bb = ((const float2*)b)[lane];
    float2 o;
    o.x = dx * rs * gg.x + bb.x;
    o.y = dy * rs * gg.y + bb.y;
    float* p = out + (size_t)row * oStride + oOff + lane * 2;
    if (OUTC) stc8(p, o); else *reinterpret_cast<float2*>(p) = o;
}

// ---------------------------------------------------------------------------
// Single persistent kernel: 9 phases, 8 fence-free barriers.
// ---------------------------------------------------------------------------
__global__ __launch_bounds__(256, 4)
void fused_all(const float* __restrict__ x, const int* __restrict__ neigh,
               const int* __restrict__ cnt,
               const float* __restrict__ gcnW, const float* __restrict__ gcnB,
               const float* __restrict__ gcnG, const float* __restrict__ gcnBb,
               const float* __restrict__ poolW, const float* __restrict__ poolB,
               const float* __restrict__ mW, const float* __restrict__ mB,
               const float* __restrict__ sg, const float* __restrict__ sb,
               float* __restrict__ out, unsigned* __restrict__ bar,
               float* __restrict__ dinv, int* __restrict__ kept,
               float* __restrict__ G, float* __restrict__ H1, float* __restrict__ H2,
               float* __restrict__ E, float* __restrict__ P,
               float* __restrict__ S1, float* __restrict__ S2, float* __restrict__ T) {
    __shared__ unsigned short shB[16 * BSTR];
    const int tid = threadIdx.x;
    const int lane = tid & 63;
    const int w = tid >> 6;
    const unsigned nb = gridDim.x;

    // ---- Phase 1: mega GEMM from x (3072 items) + deg/dedupe (32 items) ----
    for (int item = blockIdx.x; item < 3104; item += nb) {
        if (item < 3072) {
            int bx = item & 127;
            int by = item >> 7;
            int grp = by >> 3;
            int colBase = (by & 7) * 16;
            const float* W; const float* bias; float* dst; int wstr; bool relu = false;
            if (grp == 0)      { W = gcnW;  bias = gcnB;  dst = G;  wstr = 128; }
            else if (grp == 1) { W = poolW; bias = poolB; dst = E;  wstr = 128; relu = true; }
            else               { W = mW;    bias = mB;    dst = S1; wstr = 256; }
            stage_b128f(shB, W + (size_t)colBase * wstr, wstr, tid);
            __syncthreads();
            int rowBase = (bx * 4 + w) * 16;
            f32x4 acc = {0.f, 0.f, 0.f, 0.f};
            acc = mma128<false>(x, DD, rowBase, shB, lane, acc);   // x: cached
            store_tile<true>(dst, DD, 0, rowBase, colBase, lane, acc, bias, relu);
            __syncthreads();
        } else {
            int i = (item - 3072) * 256 + tid;
            int c = cnt[i];
            int nbv[KNBR];
#pragma unroll
            for (int j = 0; j < KNBR; ++j) nbv[j] = neigh[i * KNBR + j];
            int mask = 0, deg = 1;
#pragma unroll
            for (int j = 0; j < KNBR; ++j) {
                if (j < c) {
                    int v = nbv[j];
                    bool dup = (v == i);
                    for (int jj = 0; jj < j; ++jj)
                        if (nbv[jj] == v) { dup = true; }
                    if (!dup) { mask |= (1 << j); deg++; }
                }
            }
            stc4(dinv + i, rsqrtf((float)deg));
            stci(kept + i, mask);
        }
    }
    grid_barrier(bar, nb, 1);

    // ---- Phase 2: H1 = propLN(G0, resid=G0); P1 = pool(E1) ----
    for (int item = blockIdx.x; item < 2048; item += nb) {
        int row = item * 4 + w;
        prop_ln_row<true>(row, lane, G, G, dinv, kept, neigh, gcnG, gcnBb, H1, DD, 0);
        pool_row(row, lane, E, neigh, cnt, P);
    }
    grid_barrier(bar, nb, 2);

    // ---- Phase 3: z0: S1 = relu(S1p + P1@mW0R^T); z1: G1 = H1@gcnW1^T + b1 ----
    for (int item = blockIdx.x; item < 2048; item += nb) {
        int bx = item & 127, by = (item >> 7) & 7, bz = item >> 10;
        int colBase = by * 16;
        int rowBase = (bx * 4 + w) * 16;
        f32x4 acc = {0.f, 0.f, 0.f, 0.f};
        if (bz == 0) {
            stage_b128f(shB, mW + 128 + (size_t)colBase * 256, 256, tid);
            __syncthreads();
            acc = mma128<true>(P, DD, rowBase, shB, lane, acc);
            int idx = lane & 15, q = lane >> 4;
#pragma unroll
            for (int r = 0; r < 4; ++r) {
                float* p = S1 + (size_t)(rowBase + q * 4 + r) * DD + colBase + idx;
                stc4(p, fmaxf(ldc4(p) + acc[r], 0.f));
            }
            __syncthreads();
        } else {
            stage_b128f(shB, gcnW + DD * DD + (size_t)colBase * 128, 128, tid);
            __syncthreads();
            acc = mma128<true>(H1, DD, rowBase, shB, lane, acc);
            store_tile<true>(G, DD, 0, rowBase, colBase, lane, acc, gcnB + DD, false);
            __syncthreads();
        }
    }
    grid_barrier(bar, nb, 3);

    // ---- Phase 4: H2 = propLN(G1, resid=H1); P2 = pool(S1) ----
    for (int item = blockIdx.x; item < 2048; item += nb) {
        int row = item * 4 + w;
        prop_ln_row<true>(row, lane, G, H1, dinv, kept, neigh,
                          gcnG + DD, gcnBb + DD, H2, DD, 0);
        pool_row(row, lane, S1, neigh, cnt, P);
    }
    grid_barrier(bar, nb, 4);

    // ---- Phase 5: z0: T = relu([S1|P2]@mW1^T + mB1); z1: G2 = H2@gcnW2^T + b2 ----
    for (int item = blockIdx.x; item < 2048; item += nb) {
        int bx = item & 127, by = (item >> 7) & 7, bz = item >> 10;
        int colBase = by * 16;
        int rowBase = (bx * 4 + w) * 16;
        f32x4 acc = {0.f, 0.f, 0.f, 0.f};
        if (bz == 0) {
            stage_b256f(shB, mW + (size_t)DD * 2 * DD + (size_t)colBase * 256, 256, tid);
            __syncthreads();
            acc = mma128<true>(S1, DD, rowBase, shB, lane, acc);
            acc = mma128<true>(P, DD, rowBase, shB + 128, lane, acc);
            store_tile<true>(T, DD, 0, rowBase, colBase, lane, acc, mB + DD, true);
            __syncthreads();
        } else {
            stage_b128f(shB, gcnW + 2 * DD * DD + (size_t)colBase * 128, 128, tid);
            __syncthreads();
            acc = mma128<true>(H2, DD, rowBase, shB, lane, acc);
            store_tile<true>(G, DD, 0, rowBase, colBase, lane, acc, gcnB + 2 * DD, false);
            __syncthreads();
        }
    }
    grid_barrier(bar, nb, 5);

    // ---- Phase 6: outL = propLN(G2, resid=H2); S2 = LN(T + S1) ----
    for (int item = blockIdx.x; item < 2048; item += nb) {
        int row = item * 4 + w;
        prop_ln_row<false>(row, lane, G, H2, dinv, kept, neigh,
                           gcnG + 2 * DD, gcnBb + 2 * DD, out, 2 * DD, 0);
        add_ln_row<true>(row, lane, T, S1, sg, sb, S2, DD, 0);
    }
    grid_barrier(bar, nb, 6);

    // ---- Phase 7: P3 = pool(S2) ----
    for (int item = blockIdx.x; item < 2048; item += nb) {
        int row = item * 4 + w;
        pool_row(row, lane, S2, neigh, cnt, P);
    }
    grid_barrier(bar, nb, 7);

    // ---- Phase 8: T = relu([S2|P3]@mW2^T + mB2) ----
    for (int item = blockIdx.x; item < 1024; item += nb) {
        int bx = item & 127, by = item >> 7;
        int colBase = by * 16;
        int rowBase = (bx * 4 + w) * 16;
        stage_b256f(shB, mW + (size_t)2 * DD * 2 * DD + (size_t)colBase * 256, 256, tid);
        __syncthreads();
        f32x4 acc = {0.f, 0.f, 0.f, 0.f};
        acc = mma128<true>(S2, DD, rowBase, shB, lane, acc);
        acc = mma128<true>(P, DD, rowBase, shB + 128, lane, acc);
        store_tile<true>(T, DD, 0, rowBase, colBase, lane, acc, mB + 2 * DD, true);
        __syncthreads();
    }
    grid_barrier(bar, nb, 8);

    // ---- Phase 9: outR = LN(T + S2) ----
    for (int item = blockIdx.x; item < 2048; item += nb) {
        int row = item * 4 + w;
        add_ln_row<false>(row, lane, T, S2, sg + DD, sb + DD, out, 2 * DD, DD);
    }
}

extern "C" void kernel_launch(void* const* d_in, const int* in_sizes, int n_in,
                              void* d_out, int out_size, void* d_ws, size_t ws_size,
                              hipStream_t stream) {
    (void)in_sizes; (void)n_in; (void)out_size; (void)ws_size;
    const float* x      = (const float*)d_in[0];
    const int*   neigh  = (const int*)d_in[1];
    const int*   cnt    = (const int*)d_in[2];
    const float* gcnW   = (const float*)d_in[3];
    const float* gcnB   = (const float*)d_in[4];
    const float* gcnG   = (const float*)d_in[5];
    const float* gcnBb  = (const float*)d_in[6];
    const float* poolW  = (const float*)d_in[7];
    const float* poolB  = (const float*)d_in[8];
    const float* mW     = (const float*)d_in[9];
    const float* mB     = (const float*)d_in[10];
    const float* sg     = (const float*)d_in[11];
    const float* sb     = (const float*)d_in[12];
    float* out = (float*)d_out;

    char* ws = (char*)d_ws;
    unsigned* bar = (unsigned*)ws;                    // barrier counter
    float* dinv = (float*)(ws + 4 * 1024);
    int*   kept = (int*)(ws + 36 * 1024);
    float* G  = (float*)(ws + 68 * 1024);             // 4 MB each
    float* H1 = G  + NND * DD;
    float* H2 = H1 + NND * DD;
    float* E  = H2 + NND * DD;
    float* P  = E  + NND * DD;
    float* S1 = P  + NND * DD;
    float* S2 = S1 + NND * DD;
    float* T  = S2 + NND * DD;

    hipMemsetAsync(bar, 0, 256, stream);

    fused_all<<<dim3(NBLK), dim3(256), 0, stream>>>(
        x, neigh, cnt, gcnW, gcnB, gcnG, gcnBb, poolW, poolB, mW, mB,
        sg, sb, out, bar, dinv, kept, G, H1, H2, E, P, S1, S2, T);
}

// Round 10
// 213.039 us; speedup vs baseline: 3.8063x; 2.0838x over previous
//
#include <hip/hip_runtime.h>

#define NND 8192
#define KNBR 8
#define DD 128
#define EPSF 1e-5f
#define BSTR 264    // LDS B-tile row stride (shorts)
#define PSTR 130    // LDS pool-tile row stride (floats)

typedef __attribute__((ext_vector_type(8))) short bf16x8;
typedef __attribute__((ext_vector_type(4))) float f32x4;

__device__ __forceinline__ unsigned short f2bf(float f) {
    unsigned u = __float_as_uint(f);
    u += 0x7FFF + ((u >> 16) & 1);   // round-to-nearest-even
    return (unsigned short)(u >> 16);
}

// Stage 16 x 128 fp32 W rows -> bf16 LDS tile (converts on the fly).
__device__ __forceinline__ void stage_b128f(unsigned short* sh,
        const float* __restrict__ W, int wstride, int tid) {
    int r = tid >> 4;
    int c = (tid & 15) * 8;
    const float* src = W + (size_t)r * wstride + c;
    float4 lo = *(const float4*)(src);
    float4 hi = *(const float4*)(src + 4);
    bf16x8 v;
    v[0] = f2bf(lo.x); v[1] = f2bf(lo.y); v[2] = f2bf(lo.z); v[3] = f2bf(lo.w);
    v[4] = f2bf(hi.x); v[5] = f2bf(hi.y); v[6] = f2bf(hi.z); v[7] = f2bf(hi.w);
    *(bf16x8*)(sh + r * BSTR + c) = v;
}

// Stage 16 x 256 fp32 W rows -> bf16 LDS tile.
__device__ __forceinline__ void stage_b256f(unsigned short* sh,
        const float* __restrict__ W, int wstride, int tid) {
    int r = tid >> 4;
    int c = (tid & 15) * 16;
    const float* src = W + (size_t)r * wstride + c;
#pragma unroll
    for (int h = 0; h < 2; ++h) {
        float4 lo = *(const float4*)(src + h * 8);
        float4 hi = *(const float4*)(src + h * 8 + 4);
        bf16x8 v;
        v[0] = f2bf(lo.x); v[1] = f2bf(lo.y); v[2] = f2bf(lo.z); v[3] = f2bf(lo.w);
        v[4] = f2bf(hi.x); v[5] = f2bf(hi.y); v[6] = f2bf(hi.z); v[7] = f2bf(hi.w);
        *(bf16x8*)(sh + r * BSTR + c + h * 8) = v;
    }
}

__device__ __forceinline__ bf16x8 afrag(const float* __restrict__ Arow, int k0) {
    float4 lo = *(const float4*)(Arow + k0);
    float4 hi = *(const float4*)(Arow + k0 + 4);
    bf16x8 r;
    r[0] = f2bf(lo.x); r[1] = f2bf(lo.y); r[2] = f2bf(lo.z); r[3] = f2bf(lo.w);
    r[4] = f2bf(hi.x); r[5] = f2bf(hi.y); r[6] = f2bf(hi.z); r[7] = f2bf(hi.w);
    return r;
}

// One 16x16 output tile, K=128 (4 mfma). Layouts per guide §3 (m89/m91):
// A[m=lane&15][k=quad*8+j], B[k][n] from W[n][k] 16B slices, C/D col=lane&15 row=quad*4+reg.
__device__ __forceinline__ f32x4 mma128(const float* __restrict__ A, int strideA,
                                        int rowBase, const unsigned short* shB,
                                        int lane, f32x4 acc) {
    int idx = lane & 15, q = lane >> 4;
    const float* Arow = A + (size_t)(rowBase + idx) * strideA;
#pragma unroll
    for (int s = 0; s < 4; ++s) {
        bf16x8 af = afrag(Arow, s * 32 + q * 8);
        bf16x8 bf = *(const bf16x8*)(shB + idx * BSTR + s * 32 + q * 8);
        acc = __builtin_amdgcn_mfma_f32_16x16x32_bf16(af, bf, acc, 0, 0, 0);
    }
    return acc;
}

__device__ __forceinline__ void store_tile(float* __restrict__ out, int ostride,
        int oOff, int rowBase, int colBase, int lane, f32x4 c,
        const float* __restrict__ bias, bool relu) {
    int idx = lane & 15, q = lane >> 4;
    float b = bias[colBase + idx];
#pragma unroll
    for (int r = 0; r < 4; ++r) {
        float v = c[r] + b;
        if (relu) v = fmaxf(v, 0.f);
        out[(size_t)(rowBase + q * 4 + r) * ostride + oOff + colBase + idx] = v;
    }
}

// ---------------------------------------------------------------------------
// 1. Mega-GEMM from x + deg/dedupe. grid (128, 25).
//  by 0..7:  G0  = x@gcnW0^T + gcnB0
//  by 8..15: E1  = relu(x@poolW^T + poolB)
//  by 16..23: S1p = x@mW0[:, :D]^T + mB0
//  by 24:    deg/dedupe (bx<32 active)
// ---------------------------------------------------------------------------
__global__ __launch_bounds__(256)
void mega_gemm(const float* __restrict__ x, const int* __restrict__ neigh,
               const int* __restrict__ cnt,
               const float* __restrict__ gcnW, const float* __restrict__ gcnB,
               const float* __restrict__ poolW, const float* __restrict__ poolB,
               const float* __restrict__ mW, const float* __restrict__ mB,
               float* __restrict__ G, float* __restrict__ E, float* __restrict__ S,
               float* __restrict__ dinv, int* __restrict__ kept) {
    __shared__ unsigned short shB[16 * BSTR];
    const int tid = threadIdx.x;
    const int by = blockIdx.y;

    if (by == 24) {
        int i = blockIdx.x * 256 + tid;
        if (i >= NND) return;
        int c = cnt[i];
        int nbv[KNBR];
#pragma unroll
        for (int j = 0; j < KNBR; ++j) nbv[j] = neigh[i * KNBR + j];
        int mask = 0, deg = 1;
#pragma unroll
        for (int j = 0; j < KNBR; ++j) {
            if (j < c) {
                int v = nbv[j];
                bool dup = (v == i);
                for (int jj = 0; jj < j; ++jj)
                    if (nbv[jj] == v) { dup = true; }
                if (!dup) { mask |= (1 << j); deg++; }
            }
        }
        dinv[i] = rsqrtf((float)deg);
        kept[i] = mask;
        return;
    }

    const int grp = by >> 3;
    const int colBase = (by & 7) * 16;
    const float* W; const float* bias; float* dst; int wstr; bool relu = false;
    if (grp == 0)      { W = gcnW;  bias = gcnB;  dst = G; wstr = 128; }
    else if (grp == 1) { W = poolW; bias = poolB; dst = E; wstr = 128; relu = true; }
    else               { W = mW;    bias = mB;    dst = S; wstr = 256; }

    stage_b128f(shB, W + (size_t)colBase * wstr, wstr, tid);
    __syncthreads();

    const int lane = tid & 63;
    const int w = tid >> 6;
    const int rowBase = (blockIdx.x * 4 + w) * 16;
    f32x4 acc = {0.f, 0.f, 0.f, 0.f};
    acc = mma128(x, DD, rowBase, shB, lane, acc);
    store_tile(dst, DD, 0, rowBase, colBase, lane, acc, bias, relu);
}

// ---------------------------------------------------------------------------
// Dual GEMM step 3: grid (128, 8, 2).
//  z=0: S1 = relu(S1p + P @ mW0[:, D:2D]^T)   (in/out accumulate)
//  z=1: G1 = H1 @ gcnW1^T + gcnB1
// ---------------------------------------------------------------------------
__global__ __launch_bounds__(256)
void gemm_step4(const float* __restrict__ P, const float* __restrict__ H1,
                const float* __restrict__ mW, const float* __restrict__ gcnW,
                const float* __restrict__ gB1,
                float* __restrict__ S, float* __restrict__ G) {
    __shared__ unsigned short shB[16 * BSTR];
    const int tid = threadIdx.x;
    const int colBase = blockIdx.y * 16;
    const int lane = tid & 63;
    const int w = tid >> 6;
    const int rowBase = (blockIdx.x * 4 + w) * 16;
    f32x4 acc = {0.f, 0.f, 0.f, 0.f};

    if (blockIdx.z == 0) {
        stage_b128f(shB, mW + 128 + (size_t)colBase * 256, 256, tid);
        __syncthreads();
        acc = mma128(P, DD, rowBase, shB, lane, acc);
        int idx = lane & 15, q = lane >> 4;
#pragma unroll
        for (int r = 0; r < 4; ++r) {
            size_t o = (size_t)(rowBase + q * 4 + r) * DD + colBase + idx;
            S[o] = fmaxf(S[o] + acc[r], 0.f);
        }
    } else {
        stage_b128f(shB, gcnW + DD * DD + (size_t)colBase * 128, 128, tid);
        __syncthreads();
        acc = mma128(H1, DD, rowBase, shB, lane, acc);
        store_tile(G, DD, 0, rowBase, colBase, lane, acc, gB1, false);
    }
}

// ---------------------------------------------------------------------------
// Dual GEMM step 5: grid (128, 8, 2).
//  z=0: T = relu([S1 | P] @ mW1^T + mB1)   (K=256 concat)
//  z=1: G2 = H2 @ gcnW2^T + gcnB2
// ---------------------------------------------------------------------------
__global__ __launch_bounds__(256)
void gemm_step6(const float* __restrict__ S1, const float* __restrict__ P,
                const float* __restrict__ H2, const float* __restrict__ mW,
                const float* __restrict__ gcnW,
                const float* __restrict__ mB1, const float* __restrict__ gB2,
                float* __restrict__ T, float* __restrict__ G) {
    __shared__ unsigned short shB[16 * BSTR];
    const int tid = threadIdx.x;
    const int colBase = blockIdx.y * 16;
    const int lane = tid & 63;
    const int w = tid >> 6;
    const int rowBase = (blockIdx.x * 4 + w) * 16;
    f32x4 acc = {0.f, 0.f, 0.f, 0.f};

    if (blockIdx.z == 0) {
        stage_b256f(shB, mW + (size_t)DD * 2 * DD + (size_t)colBase * 256, 256, tid);
        __syncthreads();
        acc = mma128(S1, DD, rowBase, shB, lane, acc);
        acc = mma128(P, DD, rowBase, shB + 128, lane, acc);
        store_tile(T, DD, 0, rowBase, colBase, lane, acc, mB1, true);
    } else {
        stage_b128f(shB, gcnW + 2 * DD * DD + (size_t)colBase * 128, 128, tid);
        __syncthreads();
        acc = mma128(H2, DD, rowBase, shB, lane, acc);
        store_tile(G, DD, 0, rowBase, colBase, lane, acc, gB2, false);
    }
}

// ---------------------------------------------------------------------------
// Row-wise helpers (fp32, one wave per row, float2 per lane).
// ---------------------------------------------------------------------------
__device__ __forceinline__ float wave_sum(float s) {
#pragma unroll
    for (int m = 1; m < 64; m <<= 1) s += __shfl_xor(s, m, 64);
    return s;
}

__device__ __forceinline__ void prop_ln_row(int row, int lane,
        const float* __restrict__ nxt, const float* __restrict__ resid,
        const float* __restrict__ dinv, const int* __restrict__ kept,
        const int* __restrict__ neigh,
        const float* __restrict__ g, const float* __restrict__ b,
        float* __restrict__ out, int oStride, int oOff) {
    const float2* nxt2 = (const float2*)nxt;
    float di = dinv[row];
    int km = kept[row];
    float2 self = nxt2[row * 64 + lane];
    float ax = di * self.x, ay = di * self.y;
#pragma unroll
    for (int j = 0; j < KNBR; ++j) {
        if (km & (1 << j)) {
            int nb = neigh[row * KNBR + j];
            float dn = dinv[nb];
            float2 v = nxt2[nb * 64 + lane];
            ax = fmaf(dn, v.x, ax);
            ay = fmaf(dn, v.y, ay);
        }
    }
    float2 r = ((const float2*)resid)[row * 64 + lane];
    float vx = fmaxf(di * ax, 0.f) + r.x;
    float vy = fmaxf(di * ay, 0.f) + r.y;
    float mu = wave_sum(vx + vy) * (1.f / 128.f);
    float dx = vx - mu, dy = vy - mu;
    float var = wave_sum(dx * dx + dy * dy) * (1.f / 128.f);
    float rs = rsqrtf(var + EPSF);
    float2 gg = ((const float2*)g)[lane];
    float2 bb = ((const float2*)b)[lane];
    float2 o;
    o.x = dx * rs * gg.x + bb.x;
    o.y = dy * rs * gg.y + bb.y;
    *reinterpret_cast<float2*>(out + (size_t)row * oStride + oOff + lane * 2) = o;
}

__device__ __forceinline__ void pool_row(int row, int lane,
        const float* __restrict__ enc, const int* __restrict__ neigh,
        const int* __restrict__ cnt, float* __restrict__ P) {
    int c = cnt[row];
    float2 acc = make_float2(0.f, 0.f);
    if (c > 0) {
        acc = make_float2(-1e30f, -1e30f);
        for (int j = 0; j < c; ++j) {
            int nb = neigh[row * KNBR + j];
            float2 v = ((const float2*)enc)[nb * 64 + lane];
            acc.x = fmaxf(acc.x, v.x);
            acc.y = fmaxf(acc.y, v.y);
        }
    }
    ((float2*)P)[row * 64 + lane] = acc;
}

__device__ __forceinline__ void add_ln_row(int row, int lane,
        const float* __restrict__ nxt, const float* __restrict__ sprev,
        const float* __restrict__ g, const float* __restrict__ b,
        float* __restrict__ out, int oStride, int oOff) {
    float2 a = ((const float2*)nxt)[row * 64 + lane];
    float2 r = ((const float2*)sprev)[row * 64 + lane];
    float vx = a.x + r.x, vy = a.y + r.y;
    float mu = wave_sum(vx + vy) * (1.f / 128.f);
    float dx = vx - mu, dy = vy - mu;
    float var = wave_sum(dx * dx + dy * dy) * (1.f / 128.f);
    float rs = rsqrtf(var + EPSF);
    float2 gg = ((const float2*)g)[lane];
    float2 bb = ((const float2*)b)[lane];
    float2 o;
    o.x = dx * rs * gg.x + bb.x;
    o.y = dy * rs * gg.y + bb.y;
    *reinterpret_cast<float2*>(out + (size_t)row * oStride + oOff + lane * 2) = o;
}

__global__ __launch_bounds__(256)
void prop_pool_kernel(const float* __restrict__ nxt, const float* __restrict__ resid,
                      const float* __restrict__ dinv, const int* __restrict__ kept,
                      const int* __restrict__ neigh, const int* __restrict__ cnt,
                      const float* __restrict__ g, const float* __restrict__ b,
                      float* __restrict__ outH,
                      const float* __restrict__ enc, float* __restrict__ P) {
    int row = blockIdx.x * 4 + (threadIdx.x >> 6);
    int lane = threadIdx.x & 63;
    prop_ln_row(row, lane, nxt, resid, dinv, kept, neigh, g, b, outH, DD, 0);
    pool_row(row, lane, enc, neigh, cnt, P);
}

__global__ __launch_bounds__(256)
void prop_addln_kernel(const float* __restrict__ nxt, const float* __restrict__ resid,
                       const float* __restrict__ dinv, const int* __restrict__ kept,
                       const int* __restrict__ neigh,
                       const float* __restrict__ g, const float* __restrict__ b,
                       float* __restrict__ outH,
                       const float* __restrict__ snxt, const float* __restrict__ sprev,
                       const float* __restrict__ sg, const float* __restrict__ sb,
                       float* __restrict__ outS) {
    int row = blockIdx.x * 4 + (threadIdx.x >> 6);
    int lane = threadIdx.x & 63;
    prop_ln_row(row, lane, nxt, resid, dinv, kept, neigh, g, b, outH, 2 * DD, 0);
    add_ln_row(row, lane, snxt, sprev, sg, sb, outS, DD, 0);
}

// ---------------------------------------------------------------------------
// 7. Tail fused: P3 = pool(S2) -> LDS; T2 = relu([S2|P3]@mW2^T + mB2);
//    outR = LN(T2 + S2). grid (128): block = 64 rows, all 128 out cols.
// ---------------------------------------------------------------------------
__global__ __launch_bounds__(256)
void tail_kernel(const float* __restrict__ S2, const int* __restrict__ neigh,
                 const int* __restrict__ cnt, const float* __restrict__ mW,
                 const float* __restrict__ mB,
                 const float* __restrict__ sg, const float* __restrict__ sb,
                 float* __restrict__ out) {
    __shared__ float shP[64 * PSTR];           // pooled tile, ~33 KB
    __shared__ unsigned short shB[16 * BSTR];  // B tile, ~8.4 KB
    const int tid = threadIdx.x;
    const int lane = tid & 63;
    const int w = tid >> 6;
    const int rowBase = blockIdx.x * 64;
    const int idx = lane & 15, q = lane >> 4;

    // ---- pool S2 -> LDS (wave w handles local rows w*16 .. w*16+15) ----
    for (int rr = 0; rr < 16; ++rr) {
        int lrow = w * 16 + rr;
        int row = rowBase + lrow;
        int c = cnt[row];
        float2 acc = make_float2(0.f, 0.f);
        if (c > 0) {
            acc = make_float2(-1e30f, -1e30f);
            for (int j = 0; j < c; ++j) {
                int nb = neigh[row * KNBR + j];
                float2 v = *(const float2*)(S2 + (size_t)nb * DD + lane * 2);
                acc.x = fmaxf(acc.x, v.x);
                acc.y = fmaxf(acc.y, v.y);
            }
        }
        *(float2*)(shP + lrow * PSTR + lane * 2) = acc;
    }

    const float* Arow = S2 + (size_t)(rowBase + w * 16 + idx) * DD;
    const float* Prow = shP + (w * 16 + idx) * PSTR;
    const float* mW2 = mW + (size_t)2 * DD * 2 * DD;

    // ---- 8 passes over 16-col tiles, K=256 ([S2 | P3]) ----
    float acc[8][4];
    for (int p = 0; p < 8; ++p) {
        __syncthreads();   // pool complete (p=0) / shB reuse safe (p>0)
        stage_b256f(shB, mW2 + (size_t)(p * 16) * 256, 256, tid);
        __syncthreads();
        f32x4 a = {0.f, 0.f, 0.f, 0.f};
#pragma unroll
        for (int s = 0; s < 4; ++s) {   // K 0..127 from S2 (global)
            bf16x8 af = afrag(Arow, s * 32 + q * 8);
            bf16x8 bf = *(const bf16x8*)(shB + idx * BSTR + s * 32 + q * 8);
            a = __builtin_amdgcn_mfma_f32_16x16x32_bf16(af, bf, a, 0, 0, 0);
        }
#pragma unroll
        for (int s = 0; s < 4; ++s) {   // K 128..255 from LDS pool tile
            const float* pp = Prow + s * 32 + q * 8;
            float2 v0 = *(const float2*)(pp), v1 = *(const float2*)(pp + 2);
            float2 v2 = *(const float2*)(pp + 4), v3 = *(const float2*)(pp + 6);
            bf16x8 af;
            af[0] = f2bf(v0.x); af[1] = f2bf(v0.y); af[2] = f2bf(v1.x); af[3] = f2bf(v1.y);
            af[4] = f2bf(v2.x); af[5] = f2bf(v2.y); af[6] = f2bf(v3.x); af[7] = f2bf(v3.y);
            bf16x8 bf = *(const bf16x8*)(shB + idx * BSTR + 128 + s * 32 + q * 8);
            a = __builtin_amdgcn_mfma_f32_16x16x32_bf16(af, bf, a, 0, 0, 0);
        }
#pragma unroll
        for (int r = 0; r < 4; ++r) acc[p][r] = a[r];
    }

    // ---- epilogue: y = relu(acc+bias) + S2 ; outR = LN(y) ----
    // lane holds rows rowBase + w*16 + q*4 + r (r=0..3), cols p*16+idx (p=0..7)
    const int rbase = rowBase + w * 16 + q * 4;
#pragma unroll
    for (int p = 0; p < 8; ++p) {
        float bias = mB[2 * DD + p * 16 + idx];
#pragma unroll
        for (int r = 0; r < 4; ++r) {
            float v = fmaxf(acc[p][r] + bias, 0.f);
            acc[p][r] = v + S2[(size_t)(rbase + r) * DD + p * 16 + idx];
        }
    }
    float mu[4], rs[4];
#pragma unroll
    for (int r = 0; r < 4; ++r) {
        float s = 0.f;
#pragma unroll
        for (int p = 0; p < 8; ++p) s += acc[p][r];
        s += __shfl_xor(s, 1, 64); s += __shfl_xor(s, 2, 64);
        s += __shfl_xor(s, 4, 64); s += __shfl_xor(s, 8, 64);
        mu[r] = s * (1.f / 128.f);
    }
#pragma unroll
    for (int r = 0; r < 4; ++r) {
        float s = 0.f;
#pragma unroll
        for (int p = 0; p < 8; ++p) {
            float d = acc[p][r] - mu[r];
            s += d * d;
        }
        s += __shfl_xor(s, 1, 64); s += __shfl_xor(s, 2, 64);
        s += __shfl_xor(s, 4, 64); s += __shfl_xor(s, 8, 64);
        rs[r] = rsqrtf(s * (1.f / 128.f) + EPSF);
    }
#pragma unroll
    for (int p = 0; p < 8; ++p) {
        float gg = sg[DD + p * 16 + idx];
        float bb = sb[DD + p * 16 + idx];
#pragma unroll
        for (int r = 0; r < 4; ++r) {
            float o = (acc[p][r] - mu[r]) * rs[r] * gg + bb;
            out[(size_t)(rbase + r) * (2 * DD) + DD + p * 16 + idx] = o;
        }
    }
}

extern "C" void kernel_launch(void* const* d_in, const int* in_sizes, int n_in,
                              void* d_out, int out_size, void* d_ws, size_t ws_size,
                              hipStream_t stream) {
    (void)in_sizes; (void)n_in; (void)out_size; (void)ws_size;
    const float* x      = (const float*)d_in[0];
    const int*   neigh  = (const int*)d_in[1];
    const int*   cnt    = (const int*)d_in[2];
    const float* gcnW   = (const float*)d_in[3];
    const float* gcnB   = (const float*)d_in[4];
    const float* gcnG   = (const float*)d_in[5];
    const float* gcnBb  = (const float*)d_in[6];
    const float* poolW  = (const float*)d_in[7];
    const float* poolB  = (const float*)d_in[8];
    const float* mW     = (const float*)d_in[9];
    const float* mB     = (const float*)d_in[10];
    const float* sg     = (const float*)d_in[11];
    const float* sb     = (const float*)d_in[12];
    float* out = (float*)d_out;

    char* ws = (char*)d_ws;
    float* dinv = (float*)ws;                    // 32 KB
    int*   kept = (int*)(ws + 32 * 1024);        // 32 KB
    float* G  = (float*)(ws + 64 * 1024);        // 4 MB each
    float* H1 = G  + NND * DD;
    float* H2 = H1 + NND * DD;
    float* E  = H2 + NND * DD;
    float* P  = E  + NND * DD;
    float* S1 = P  + NND * DD;
    float* S2 = S1 + NND * DD;
    float* T  = S2 + NND * DD;

    dim3 blk(256);
    dim3 mgrid(NND / 64, 25);        // 24 GEMM slices + 1 deg slice
    dim3 dgrid(NND / 64, 8, 2);
    dim3 rgrid(NND / 4);

    // 1. [G0 | E1 | S1p] from x  +  deg/dedupe
    mega_gemm<<<mgrid, blk, 0, stream>>>(x, neigh, cnt, gcnW, gcnB, poolW, poolB,
                                         mW, mB, G, E, S1, dinv, kept);
    // 2. H1 = propLN(G0, resid=G0); P = pool(E1)
    prop_pool_kernel<<<rgrid, blk, 0, stream>>>(G, G, dinv, kept, neigh, cnt,
                                                gcnG, gcnBb, H1, E, P);
    // 3. S1 = relu(S1p + P@mW0R^T); G = H1@gcnW1^T + b1
    gemm_step4<<<dgrid, blk, 0, stream>>>(P, H1, mW, gcnW, gcnB + DD, S1, G);
    // 4. H2 = propLN(G, resid=H1); P = pool(S1)
    prop_pool_kernel<<<rgrid, blk, 0, stream>>>(G, H1, dinv, kept, neigh, cnt,
                                                gcnG + DD, gcnBb + DD, H2, S1, P);
    // 5. T = relu([S1|P]@mW1^T + mB1); G = H2@gcnW2^T + b2
    gemm_step6<<<dgrid, blk, 0, stream>>>(S1, P, H2, mW, gcnW,
                                          mB + DD, gcnB + 2 * DD, T, G);
    // 6. outL = propLN(G, resid=H2); S2 = LN(T + S1)
    prop_addln_kernel<<<rgrid, blk, 0, stream>>>(G, H2, dinv, kept, neigh,
                                                 gcnG + 2 * DD, gcnBb + 2 * DD,
                                                 out, T, S1, sg, sb, S2);
    // 7. outR = LN(relu([S2|pool(S2)]@mW2^T + mB2) + S2)
    tail_kernel<<<dim3(NND / 64), blk, 0, stream>>>(S2, neigh, cnt, mW, mB,
                                                    sg, sb, out);
}